// Round 2
// baseline (492.151 us; speedup 1.0000x reference)
//
#include <hip/hip_runtime.h>
#include <hip/hip_bf16.h>

#define HW   16384
#define WIDTH 128
#define CIN  192
#define C3   576
#define NB   4
#define CH   48

// ---------------------------------------------------------------------------
// Channel-mix GEMM: out[b,o,p] = sum_c W[b?,o,c] * in[b,c,p]
// Tile: 64 o x 128 p, K-chunks of 16, double-buffered LDS (1 sync/chunk).
// X tile staged via global_load_lds width=16 (dest is wave-uniform + lane*16:
// byte offset = 16*s, s = t + i*256). W tile reg-staged (4 scalars/thread).
// Used for qkv conv1x1 (W shared across batch) and for the fused
// (w_out @ A_blockdiag) @ v final GEMM (per-batch W).
// ---------------------------------------------------------------------------
__global__ __launch_bounds__(256) void k_cmix_gemm(
    const float* __restrict__ in, const float* __restrict__ wmat,
    float* __restrict__ out, int inBatchStride, int outBatchStride, int wBatchStride)
{
  __shared__ __align__(16) float Wl[2][16][68];   // [buf][k][o], padded
  __shared__ __align__(16) float Xl[2][16][128];  // [buf][k][p], linear (gl_lds dest)
  const int b = blockIdx.z;
  const int oBase = blockIdx.y * 64;
  const int pBase = blockIdx.x * 128;
  const float* wb  = wmat + (size_t)b * wBatchStride + (size_t)oBase * CIN;
  const float* inb = in   + (size_t)b * inBatchStride + pBase;
  float*       outb = out + (size_t)b * outBatchStride + pBase;
  const int t = threadIdx.x;
  const int tx = t & 31, ty = t >> 5;
  const int o0 = ty * 8, p0 = tx * 4;

  // per-thread staging decode (constant across chunks)
  int wkk[4], woo[4];
#pragma unroll
  for (int i = 0; i < 4; i++) { int lin = t + i * 256; wkk[i] = lin & 15; woo[i] = lin >> 4; }
  int xs[2], xkk[2], xpp[2];
#pragma unroll
  for (int i = 0; i < 2; i++) { xs[i] = t + i * 256; xkk[i] = xs[i] >> 5; xpp[i] = (xs[i] & 31) * 4; }

  float acc[8][4];
#pragma unroll
  for (int i = 0; i < 8; i++)
#pragma unroll
    for (int j = 0; j < 4; j++) acc[i][j] = 0.f;

  float wr[4];

#define STAGE_X(buf, k0)                                                        \
  {                                                                             \
    _Pragma("unroll")                                                           \
    for (int i = 0; i < 2; i++) {                                               \
      const float* gsrc = inb + (size_t)((k0) + xkk[i]) * HW + xpp[i];          \
      float* ldst = &Xl[buf][0][0] + 4 * xs[i];  /* == wave base + lane*16 */   \
      __builtin_amdgcn_global_load_lds(                                         \
          (__attribute__((address_space(1))) void*)(void*)gsrc,                 \
          (__attribute__((address_space(3))) void*)(void*)ldst, 16, 0, 0);      \
    }                                                                           \
  }
#define LOAD_W(k0)                                                              \
  {                                                                             \
    _Pragma("unroll")                                                           \
    for (int i = 0; i < 4; i++) wr[i] = wb[woo[i] * CIN + (k0) + wkk[i]];       \
  }
#define STORE_W(buf)                                                            \
  {                                                                             \
    _Pragma("unroll")                                                           \
    for (int i = 0; i < 4; i++) Wl[buf][wkk[i]][woo[i]] = wr[i];                \
  }

  // prologue: chunk 0 into buf 0
  STAGE_X(0, 0);
  LOAD_W(0);
  STORE_W(0);
  __syncthreads();   // implies vmcnt(0) drain -> Xl[0] ready

  int cur = 0;
  for (int k0 = 0; k0 < CIN; k0 += 16) {
    const bool more = (k0 + 16 < CIN);
    if (more) {
      STAGE_X(cur ^ 1, k0 + 16);   // async into the idle buffer
      LOAD_W(k0 + 16);             // waits folded in by compiler at STORE_W
    }
#pragma unroll
    for (int kk = 0; kk < 16; kk++) {
      float4 wa  = *(float4*)&Wl[cur][kk][o0];
      float4 wb4 = *(float4*)&Wl[cur][kk][o0 + 4];
      float4 xv  = *(float4*)&Xl[cur][kk][p0];
      float wreg[8] = {wa.x, wa.y, wa.z, wa.w, wb4.x, wb4.y, wb4.z, wb4.w};
      float xreg[4] = {xv.x, xv.y, xv.z, xv.w};
#pragma unroll
      for (int i = 0; i < 8; i++)
#pragma unroll
        for (int j = 0; j < 4; j++) acc[i][j] += wreg[i] * xreg[j];
    }
    if (more) {
      STORE_W(cur ^ 1);
      __syncthreads();             // drains vmcnt -> next buffer fully staged
      cur ^= 1;
    }
  }
#pragma unroll
  for (int i = 0; i < 8; i++) {
    float4 v = make_float4(acc[i][0], acc[i][1], acc[i][2], acc[i][3]);
    *(float4*)&outb[(size_t)(oBase + o0 + i) * HW + p0] = v;
  }
#undef STAGE_X
#undef LOAD_W
#undef STORE_W
}

// ---------------------------------------------------------------------------
// Depthwise 3x3 conv (pad 1), IN-PLACE per plane via LDS row ring, fused with
// the q/k L2-row-norm reduction (channels 0..383 of each batch).
// One block owns one (b,ch) 128x128 plane; 16 chunks of 8 rows.
// ---------------------------------------------------------------------------
__global__ __launch_bounds__(256) void k_dwconv_norm(
    float* __restrict__ buf, const float* __restrict__ wdw, float* __restrict__ inorm)
{
  const int bo = blockIdx.x;          // b*576 + ch
  const int ch = bo % C3;
  const int b  = bo / C3;
  float* plane = buf + (size_t)bo * HW;
  float wv[9];
#pragma unroll
  for (int i = 0; i < 9; i++) wv[i] = wdw[ch * 9 + i];

  __shared__ float ring[16][128];
  __shared__ float red[4];
  const int tx = threadIdx.x & 31;
  const int ty = threadIdx.x >> 5;
  const int x0 = tx * 4;

  // prologue: input rows 0..8 into ring (slot = row % 16)
  *(float4*)&ring[ty][x0] = *(const float4*)&plane[ty * WIDTH + x0];
  if (ty == 0) *(float4*)&ring[8][x0] = *(const float4*)&plane[8 * WIDTH + x0];

  float ssum = 0.f;

  for (int c = 0; c < 16; c++) {
    __syncthreads();                  // ring loads visible
    const int y = c * 8 + ty;
    float a0 = 0.f, a1 = 0.f, a2 = 0.f, a3 = 0.f;
#pragma unroll
    for (int dy = 0; dy < 3; dy++) {
      int yy = y + dy - 1;
      if (yy < 0 || yy > 127) continue;     // zero-pad rows
      const float* r = ring[yy & 15];
      float4 cc = *(const float4*)&r[x0];
      float left  = (x0 > 0) ? r[x0 - 1] : 0.f;          // zero-pad cols
      float right = (x0 + 4 < WIDTH) ? r[x0 + 4] : 0.f;
      float w0 = wv[dy * 3 + 0], w1 = wv[dy * 3 + 1], w2 = wv[dy * 3 + 2];
      a0 += w0 * left + w1 * cc.x + w2 * cc.y;
      a1 += w0 * cc.x + w1 * cc.y + w2 * cc.z;
      a2 += w0 * cc.y + w1 * cc.z + w2 * cc.w;
      a3 += w0 * cc.z + w1 * cc.w + w2 * right;
    }
    __syncthreads();                  // everyone done reading ring this chunk
    *(float4*)&plane[y * WIDTH + x0] = make_float4(a0, a1, a2, a3);
    ssum += a0 * a0 + a1 * a1 + a2 * a2 + a3 * a3;
    if (c < 15) {                     // load input rows 8c+9 .. 8c+16
      int rrow = c * 8 + 9 + ty;
      if (rrow < 128)
        *(float4*)&ring[rrow & 15][x0] = *(const float4*)&plane[rrow * WIDTH + x0];
    }
  }

  if (ch < 384) {                     // q or k plane: emit 1/max(||row||,1e-12)
    for (int off = 32; off; off >>= 1) ssum += __shfl_down(ssum, off, 64);
    if ((threadIdx.x & 63) == 0) red[threadIdx.x >> 6] = ssum;
    __syncthreads();
    if (threadIdx.x == 0) {
      float tot = red[0] + red[1] + red[2] + red[3];
      inorm[b * 384 + ch] = 1.0f / fmaxf(sqrtf(tot), 1e-12f);
    }
  }
}

// ---------------------------------------------------------------------------
// attn partials: per (b,h) 48x48 Gram matrix over 16384 tokens, split-K into
// 32 chunks of 512 (deterministic; no atomics). Norm/temp folded in later.
// ---------------------------------------------------------------------------
__global__ __launch_bounds__(256) void k_attn_part(
    const float* __restrict__ qkv, float* __restrict__ part)
{
  const int bh = blockIdx.y;          // b*4 + h
  const int b = bh >> 2, h = bh & 3;
  const int pbase = blockIdx.x * 512;
  const float* qb = qkv + ((size_t)b * C3 +       h * CH) * HW + pbase;
  const float* kb = qkv + ((size_t)b * C3 + 192 + h * CH) * HW + pbase;
  __shared__ float Ql[48][33], Kl[48][33];   // padded: conflict-free
  const int t = threadIdx.x;
  const int c0 = (t & 15) * 3, d0 = (t >> 4) * 3;
  float acc[3][3];
#pragma unroll
  for (int i = 0; i < 3; i++)
#pragma unroll
    for (int j = 0; j < 3; j++) acc[i][j] = 0.f;

  for (int chk = 0; chk < 16; chk++) {
    const int pp0 = chk * 32;
#pragma unroll
    for (int i = 0; i < 6; i++) {
      int lin = t + i * 256;
      int cc = lin >> 5, pp = lin & 31;
      Ql[cc][pp] = qb[(size_t)cc * HW + pp0 + pp];
      Kl[cc][pp] = kb[(size_t)cc * HW + pp0 + pp];
    }
    __syncthreads();
#pragma unroll
    for (int pp = 0; pp < 32; pp++) {
      float q0 = Ql[c0][pp], q1 = Ql[c0 + 1][pp], q2 = Ql[c0 + 2][pp];
      float k0v = Kl[d0][pp], k1v = Kl[d0 + 1][pp], k2v = Kl[d0 + 2][pp];
      acc[0][0] += q0 * k0v; acc[0][1] += q0 * k1v; acc[0][2] += q0 * k2v;
      acc[1][0] += q1 * k0v; acc[1][1] += q1 * k1v; acc[1][2] += q1 * k2v;
      acc[2][0] += q2 * k0v; acc[2][1] += q2 * k1v; acc[2][2] += q2 * k2v;
    }
    __syncthreads();
  }
  float* pb = part + ((size_t)blockIdx.x * 16 + bh) * 2304;
#pragma unroll
  for (int i = 0; i < 3; i++)
#pragma unroll
    for (int j = 0; j < 3; j++)
      pb[(c0 + i) * 48 + d0 + j] = acc[i][j];
}

__global__ void k_attn_reduce(const float* __restrict__ part, float* __restrict__ attn)
{
  int idx = blockIdx.x * 256 + threadIdx.x;   // 36864 total
  float s = 0.f;
  for (int ps = 0; ps < 32; ps++) s += part[(size_t)ps * 36864 + idx];
  attn[idx] = s;
}

// ---------------------------------------------------------------------------
// Per-row: apply inorm_q*inorm_k*temp, rank all 48 entries once (tie-break by
// index == lax.top_k), then combine all four masked softmaxes weighted by
// attn_w into a single 48x48 matrix A.
// ---------------------------------------------------------------------------
__global__ __launch_bounds__(64) void k_topk_combine(
    const float* __restrict__ attn, const float* __restrict__ inorm,
    const float* __restrict__ temp, const float* __restrict__ attnw,
    float* __restrict__ A)
{
  const int bh = blockIdx.x;
  const int b = bh >> 2, h = bh & 3;
  __shared__ float Sv[48][49];
  const float tmp = temp[h];
  const float* ar = attn + (size_t)bh * 2304;
  for (int lin = threadIdx.x; lin < 2304; lin += 64) {
    int c = lin / 48, d = lin - (lin / 48) * 48;
    Sv[c][d] = ar[lin] * inorm[b * 384 + h * 48 + c]
                       * inorm[b * 384 + 192 + h * 48 + d] * tmp;
  }
  __syncthreads();
  if (threadIdx.x < 48) {
    const int c = threadIdx.x;
    float m = -3.4e38f;
    for (int d = 0; d < 48; d++) m = fmaxf(m, Sv[c][d]);
    unsigned long long mk0 = 0, mk1 = 0, mk2 = 0, mk3 = 0;
    float S0 = 0.f, S1 = 0.f, S2 = 0.f, S3 = 0.f;
    for (int d = 0; d < 48; d++) {
      float vd = Sv[c][d];
      int cnt = 0;
      for (int d2 = 0; d2 < 48; d2++) {
        float v2 = Sv[c][d2];
        cnt += (v2 > vd) || (v2 == vd && d2 < d);
      }
      float e = expf(vd - m);
      if (cnt < 24) { mk0 |= 1ull << d; S0 += e; }
      if (cnt < 32) { mk1 |= 1ull << d; S1 += e; }
      if (cnt < 36) { mk2 |= 1ull << d; S2 += e; }
      if (cnt < 38) { mk3 |= 1ull << d; S3 += e; }
    }
    float w0 = attnw[0] / S0, w1 = attnw[1] / S1;
    float w2 = attnw[2] / S2, w3 = attnw[3] / S3;
    float* Ao = A + ((size_t)bh * 48 + c) * 48;
    for (int d = 0; d < 48; d++) {
      float e = expf(Sv[c][d] - m);
      float a = 0.f;
      if ((mk0 >> d) & 1) a += w0 * e;
      if ((mk1 >> d) & 1) a += w1 * e;
      if ((mk2 >> d) & 1) a += w2 * e;
      if ((mk3 >> d) & 1) a += w3 * e;
      Ao[d] = a;
    }
  }
}

// ---------------------------------------------------------------------------
// M[b] = w_out @ A_blockdiag[b]  (192x192 per batch) — folds the attention
// apply and the final conv1x1 into a single downstream GEMM.
// ---------------------------------------------------------------------------
__global__ void k_mbuild(const float* __restrict__ wout, const float* __restrict__ A,
                         float* __restrict__ M)
{
  const int o = blockIdx.x;     // 0..191
  const int b = blockIdx.y;
  const int j = threadIdx.x;    // 0..191
  const int h = j / 48, d = j - (j / 48) * 48;
  const float* Ab = A + ((size_t)(b * 4 + h) * 48) * 48 + d;
  const float* wrow = wout + o * 192 + h * 48;
  float s = 0.f;
#pragma unroll
  for (int c = 0; c < 48; c++) s += wrow[c] * Ab[c * 48];
  M[((size_t)b * 192 + o) * 192 + j] = s;
}

// ---------------------------------------------------------------------------
extern "C" void kernel_launch(void* const* d_in, const int* in_sizes, int n_in,
                              void* d_out, int out_size, void* d_ws, size_t ws_size,
                              hipStream_t stream)
{
  const float* x     = (const float*)d_in[0];
  const float* wqkv  = (const float*)d_in[1];
  const float* wdw   = (const float*)d_in[2];
  const float* wout  = (const float*)d_in[3];
  const float* temp  = (const float*)d_in[4];
  const float* attnw = (const float*)d_in[5];
  float* outp = (float*)d_out;
  float* ws = (float*)d_ws;

  // workspace layout (floats) — total 39,151,104 floats = 149.4 MiB
  float* qkvbuf    = ws;                      // 4*576*16384 (conv1x1 out, dwconv in-place)
  float* inorm     = qkvbuf + 37748736;       // 1536
  float* attn_part = inorm + 1536;            // 32*16*2304
  float* attn_raw  = attn_part + 1179648;     // 36864
  float* Acomb     = attn_raw + 36864;        // 36864
  float* Mmat      = Acomb + 36864;           // 4*192*192

  // 1) qkv = conv1x1(x, w_qkv): per-batch GEMM 576 x 16384 x 192
  k_cmix_gemm<<<dim3(128, 9, NB), 256, 0, stream>>>(
      x, wqkv, qkvbuf, CIN * HW, C3 * HW, 0);

  // 2) depthwise 3x3 in-place + fused q/k row-norm
  k_dwconv_norm<<<NB * C3, 256, 0, stream>>>(qkvbuf, wdw, inorm);

  // 3) attn Gram partials + deterministic reduce
  k_attn_part<<<dim3(32, 16), 256, 0, stream>>>(qkvbuf, attn_part);
  k_attn_reduce<<<144, 256, 0, stream>>>(attn_part, attn_raw);

  // 4) combined top-k softmax matrix A
  k_topk_combine<<<16, 64, 0, stream>>>(attn_raw, inorm, temp, attnw, Acomb);

  // 5) M = w_out @ A_blockdiag (per batch)
  k_mbuild<<<dim3(192, NB), 192, 0, stream>>>(wout, Acomb, Mmat);

  // 6) out = M @ v  (192 x 16384 x 192 per batch)
  k_cmix_gemm<<<dim3(128, 3, NB), 256, 0, stream>>>(
      qkvbuf + (size_t)384 * HW, Mmat, outp, C3 * HW, CIN * HW, CIN * CIN);
}

// Round 7
// 457.869 us; speedup vs baseline: 1.0749x; 1.0749x over previous
//
#include <hip/hip_runtime.h>
#include <hip/hip_bf16.h>

#define HW   16384
#define WIDTH 128
#define CIN  192
#define C3   576
#define NB   4
#define CH   48

typedef __attribute__((ext_vector_type(8))) __bf16 bf16x8;
typedef __attribute__((ext_vector_type(4))) float f32x4;

__device__ __forceinline__ unsigned short f2bf(float f) {
  unsigned u = __float_as_uint(f);
  unsigned r = (u + 0x7fffu + ((u >> 16) & 1u)) >> 16;   // RNE
  return (unsigned short)r;
}
__device__ __forceinline__ float bf2f(unsigned short h) {
  return __uint_as_float((unsigned)h << 16);
}

// ---------------------------------------------------------------------------
// Pack w_qkv (576x192 fp32) into MFMA A-fragment layout, split-bf16 hi/lo.
// Frag elem j of lane l, k-tile kg:  k = kg*32 + (l>>4)*4 + (j&3) + 16*(j>>2)
// (B-fragments are gathered with the same (g,j)->k bijection — consistent
// A/B k-permutation cancels inside the MFMA dot product).
// hi plane at wp[0..110591], lo plane at wp[110592..].
// ---------------------------------------------------------------------------
__global__ void k_wpack(const float* __restrict__ w, unsigned short* __restrict__ wp)
{
  const int bid = blockIdx.x;            // mt*6 + kg, mt in [0,36)
  const int mt = bid / 6, kg = bid - 6 * mt;
  const int l = threadIdx.x;             // 0..63
  const int m = mt * 16 + (l & 15);
  const int g = l >> 4;
  unsigned short vh[8], vl[8];
#pragma unroll
  for (int j = 0; j < 8; j++) {
    int k = kg * 32 + (g << 2) + (j & 3) + ((j >> 2) << 4);
    float x = w[m * 192 + k];
    vh[j] = f2bf(x);
    vl[j] = f2bf(x - bf2f(vh[j]));
  }
  *(uint4*)(wp + ((size_t)bid * 64 + l) * 8) = *(uint4*)vh;
  *(uint4*)(wp + 110592 + ((size_t)bid * 64 + l) * 8) = *(uint4*)vl;
}

// ---------------------------------------------------------------------------
// Split-bf16 MFMA channel-mix GEMM: out[b,o,p] = sum_c W[o,c] * B[b,c,p]
// x*y ~= hi*hi' + hi*lo' + lo*hi' (fp32 accum; lo*lo' <= 2^-18 dropped).
// BM=192 (3 m-frags/wave), BN=128. 512 thr = 8 waves (4 wm x 2 wn), wave
// tile 48x64. K staged in 2 halves of 96 rows. B: fp32 global -> {hi,lo}
// bf16 LDS, TRANSPOSED + padded layout Bt[pl][ns][col][k(96)+4pad] so each
// fragment is two contiguous 8-byte runs -> plain C++ uint2 reads
// (ds_read_b64), no inline asm, no address-space casts.
// A: prepacked hi/lo frags from global (L2-resident), lo at +aLoOff elems.
// ---------------------------------------------------------------------------
__global__ __launch_bounds__(512) void k_gemm_sb(
    const float* __restrict__ Bsrc, const unsigned short* __restrict__ Afrag,
    float* __restrict__ out, size_t bBatch, size_t aBatch, size_t outBatch,
    size_t aLoOff)
{
  __shared__ unsigned short Bt[2][8][16][100];   // 51.2 KB: [hi/lo][ns][col][klocal]
  const int b = blockIdx.z, mb = blockIdx.y;
  const int pBase = blockIdx.x * 128;
  const int t = threadIdx.x;
  const int lane = t & 63, w = t >> 6;
  const int wm = w >> 1, wn = w & 1;
  const int g = lane >> 4, c = lane & 15;
  const float* Bp = Bsrc + (size_t)b * bBatch + pBase;
  const unsigned short* Ap = Afrag + (size_t)b * aBatch;
  const int mtBase = mb * 12 + wm * 3;

  f32x4 acc[3][4];
#pragma unroll
  for (int i = 0; i < 3; i++)
#pragma unroll
    for (int nf = 0; nf < 4; nf++) acc[i][nf] = f32x4{0.f, 0.f, 0.f, 0.f};

  for (int kh = 0; kh < 2; kh++) {
    if (kh) __syncthreads();             // previous half's readers done
    // ---- stage: wave w owns ns=w (cols w*16..+15); 96 k-rows this half ----
    {
      const int kr = lane >> 2, nc = (lane & 3) * 4;
      const float* src = Bp + w * 16 + nc;
#pragma unroll
      for (int i = 0; i < 6; i++) {
        int kl = i * 16 + kr;            // 0..95
        float4 v = *(const float4*)&src[(size_t)(kh * 96 + kl) * HW];
        float xs[4] = {v.x, v.y, v.z, v.w};
#pragma unroll
        for (int q = 0; q < 4; q++) {
          unsigned short hh = f2bf(xs[q]);
          Bt[0][w][nc + q][kl] = hh;
          Bt[1][w][nc + q][kl] = f2bf(xs[q] - bf2f(hh));
        }
      }
    }
    __syncthreads();
    // ---- compute: 3 k-tiles of 32 within this half ----
#pragma unroll
    for (int ks = 0; ks < 3; ks++) {
      const int kg = kh * 3 + ks;        // global 32-row tile index 0..5
      bf16x8 afh[3], afl[3];
#pragma unroll
      for (int i = 0; i < 3; i++) {
        size_t fo = (((size_t)(mtBase + i) * 6 + kg) * 64 + lane) * 8;
        afh[i] = __builtin_bit_cast(bf16x8, *(const uint4*)(Ap + fo));
        afl[i] = __builtin_bit_cast(bf16x8, *(const uint4*)(Ap + aLoOff + fo));
      }
      const int k0 = ks * 32 + g * 4;    // frag k-base within half (<= 76)
#pragma unroll
      for (int nf = 0; nf < 4; nf++) {
        const int ns = wn * 4 + nf;
        const unsigned short* ch = &Bt[0][ns][c][0];
        const unsigned short* cl = &Bt[1][ns][c][0];
        uint2 h0 = *(const uint2*)(ch + k0);
        uint2 h1 = *(const uint2*)(ch + k0 + 16);
        uint2 l0 = *(const uint2*)(cl + k0);
        uint2 l1 = *(const uint2*)(cl + k0 + 16);
        uint4 bw;
        bw.x = h0.x; bw.y = h0.y; bw.z = h1.x; bw.w = h1.y;
        bf16x8 bfh = __builtin_bit_cast(bf16x8, bw);
        bw.x = l0.x; bw.y = l0.y; bw.z = l1.x; bw.w = l1.y;
        bf16x8 bfl = __builtin_bit_cast(bf16x8, bw);
#pragma unroll
        for (int i = 0; i < 3; i++) {
          acc[i][nf] = __builtin_amdgcn_mfma_f32_16x16x32_bf16(afh[i], bfl, acc[i][nf], 0, 0, 0);
          acc[i][nf] = __builtin_amdgcn_mfma_f32_16x16x32_bf16(afl[i], bfh, acc[i][nf], 0, 0, 0);
          acc[i][nf] = __builtin_amdgcn_mfma_f32_16x16x32_bf16(afh[i], bfh, acc[i][nf], 0, 0, 0);
        }
      }
    }
  }

  // ---- epilogue: C/D layout col=lane&15, row=(lane>>4)*4+reg (m89) ----
  const int r0 = g * 4, c0 = c;
  float* op = out + (size_t)b * outBatch + pBase + wn * 64 + c0;
#pragma unroll
  for (int i = 0; i < 3; i++) {
    int mrow = (mtBase + i) * 16 + r0;
#pragma unroll
    for (int nf = 0; nf < 4; nf++)
#pragma unroll
      for (int r = 0; r < 4; r++)
        op[(size_t)(mrow + r) * HW + nf * 16] = acc[i][nf][r];
  }
}

// ---------------------------------------------------------------------------
// Depthwise 3x3 conv (pad 1), IN-PLACE per plane via LDS row ring, fused with
// the q/k L2-row-norm reduction (channels 0..383 of each batch).
// ---------------------------------------------------------------------------
__global__ __launch_bounds__(256) void k_dwconv_norm(
    float* __restrict__ buf, const float* __restrict__ wdw, float* __restrict__ inorm)
{
  const int bo = blockIdx.x;          // b*576 + ch
  const int ch = bo % C3;
  const int b  = bo / C3;
  float* plane = buf + (size_t)bo * HW;
  float wv[9];
#pragma unroll
  for (int i = 0; i < 9; i++) wv[i] = wdw[ch * 9 + i];

  __shared__ float ring[16][128];
  __shared__ float red[4];
  const int tx = threadIdx.x & 31;
  const int ty = threadIdx.x >> 5;
  const int x0 = tx * 4;

  *(float4*)&ring[ty][x0] = *(const float4*)&plane[ty * WIDTH + x0];
  if (ty == 0) *(float4*)&ring[8][x0] = *(const float4*)&plane[8 * WIDTH + x0];

  float ssum = 0.f;

  for (int c = 0; c < 16; c++) {
    __syncthreads();
    const int y = c * 8 + ty;
    float a0 = 0.f, a1 = 0.f, a2 = 0.f, a3 = 0.f;
#pragma unroll
    for (int dy = 0; dy < 3; dy++) {
      int yy = y + dy - 1;
      if (yy < 0 || yy > 127) continue;
      const float* r = ring[yy & 15];
      float4 cc = *(const float4*)&r[x0];
      float left  = (x0 > 0) ? r[x0 - 1] : 0.f;
      float right = (x0 + 4 < WIDTH) ? r[x0 + 4] : 0.f;
      float w0 = wv[dy * 3 + 0], w1 = wv[dy * 3 + 1], w2 = wv[dy * 3 + 2];
      a0 += w0 * left + w1 * cc.x + w2 * cc.y;
      a1 += w0 * cc.x + w1 * cc.y + w2 * cc.z;
      a2 += w0 * cc.y + w1 * cc.z + w2 * cc.w;
      a3 += w0 * cc.z + w1 * cc.w + w2 * right;
    }
    __syncthreads();
    *(float4*)&plane[y * WIDTH + x0] = make_float4(a0, a1, a2, a3);
    ssum += a0 * a0 + a1 * a1 + a2 * a2 + a3 * a3;
    if (c < 15) {
      int rrow = c * 8 + 9 + ty;
      if (rrow < 128)
        *(float4*)&ring[rrow & 15][x0] = *(const float4*)&plane[rrow * WIDTH + x0];
    }
  }

  if (ch < 384) {
    for (int off = 32; off; off >>= 1) ssum += __shfl_down(ssum, off, 64);
    if ((threadIdx.x & 63) == 0) red[threadIdx.x >> 6] = ssum;
    __syncthreads();
    if (threadIdx.x == 0) {
      float tot = red[0] + red[1] + red[2] + red[3];
      inorm[b * 384 + ch] = 1.0f / fmaxf(sqrtf(tot), 1e-12f);
    }
  }
}

// ---------------------------------------------------------------------------
// attn partials: per (b,h) 48x48 Gram over 16384 tokens, split-K 16 chunks
// of 1024 (deterministic; no atomics). Norm/temp folded in later.
// ---------------------------------------------------------------------------
__global__ __launch_bounds__(256) void k_attn_part(
    const float* __restrict__ qkv, float* __restrict__ part)
{
  const int bh = blockIdx.y;
  const int b = bh >> 2, h = bh & 3;
  const int pbase = blockIdx.x * 1024;
  const float* qb = qkv + ((size_t)b * C3 +       h * CH) * HW + pbase;
  const float* kb = qkv + ((size_t)b * C3 + 192 + h * CH) * HW + pbase;
  __shared__ float Ql[48][33], Kl[48][33];
  const int t = threadIdx.x;
  const int c0 = (t & 15) * 3, d0 = (t >> 4) * 3;
  float acc[3][3];
#pragma unroll
  for (int i = 0; i < 3; i++)
#pragma unroll
    for (int j = 0; j < 3; j++) acc[i][j] = 0.f;

  for (int chk = 0; chk < 32; chk++) {
    const int pp0 = chk * 32;
#pragma unroll
    for (int i = 0; i < 6; i++) {
      int lin = t + i * 256;
      int cc = lin >> 5, pp = lin & 31;
      Ql[cc][pp] = qb[(size_t)cc * HW + pp0 + pp];
      Kl[cc][pp] = kb[(size_t)cc * HW + pp0 + pp];
    }
    __syncthreads();
#pragma unroll
    for (int pp = 0; pp < 32; pp++) {
      float q0 = Ql[c0][pp], q1 = Ql[c0 + 1][pp], q2 = Ql[c0 + 2][pp];
      float k0v = Kl[d0][pp], k1v = Kl[d0 + 1][pp], k2v = Kl[d0 + 2][pp];
      acc[0][0] += q0 * k0v; acc[0][1] += q0 * k1v; acc[0][2] += q0 * k2v;
      acc[1][0] += q1 * k0v; acc[1][1] += q1 * k1v; acc[1][2] += q1 * k2v;
      acc[2][0] += q2 * k0v; acc[2][1] += q2 * k1v; acc[2][2] += q2 * k2v;
    }
    __syncthreads();
  }
  float* pb = part + ((size_t)blockIdx.x * 16 + bh) * 2304;
#pragma unroll
  for (int i = 0; i < 3; i++)
#pragma unroll
    for (int j = 0; j < 3; j++)
      pb[(c0 + i) * 48 + d0 + j] = acc[i][j];
}

// ---------------------------------------------------------------------------
// Fused: split-K reduce + norm/temp scale + rank-once + 4-way masked softmax
// combine weighted by attn_w.
// ---------------------------------------------------------------------------
__global__ __launch_bounds__(64) void k_topk_combine(
    const float* __restrict__ part, const float* __restrict__ inorm,
    const float* __restrict__ temp, const float* __restrict__ attnw,
    float* __restrict__ A)
{
  const int bh = blockIdx.x;
  const int b = bh >> 2, h = bh & 3;
  __shared__ float Sv[48][49];
  const float tmp = temp[h];
  for (int lin = threadIdx.x; lin < 2304; lin += 64) {
    float s = 0.f;
    for (int ps = 0; ps < 16; ps++)
      s += part[((size_t)ps * 16 + bh) * 2304 + lin];
    int c = lin / 48, d = lin - (lin / 48) * 48;
    Sv[c][d] = s * inorm[b * 384 + h * 48 + c]
                 * inorm[b * 384 + 192 + h * 48 + d] * tmp;
  }
  __syncthreads();
  if (threadIdx.x < 48) {
    const int c = threadIdx.x;
    float m = -3.4e38f;
    for (int d = 0; d < 48; d++) m = fmaxf(m, Sv[c][d]);
    unsigned long long mk0 = 0, mk1 = 0, mk2 = 0, mk3 = 0;
    float S0 = 0.f, S1 = 0.f, S2 = 0.f, S3 = 0.f;
    for (int d = 0; d < 48; d++) {
      float vd = Sv[c][d];
      int cnt = 0;
      for (int d2 = 0; d2 < 48; d2++) {
        float v2 = Sv[c][d2];
        cnt += (v2 > vd) || (v2 == vd && d2 < d);
      }
      float e = expf(vd - m);
      if (cnt < 24) { mk0 |= 1ull << d; S0 += e; }
      if (cnt < 32) { mk1 |= 1ull << d; S1 += e; }
      if (cnt < 36) { mk2 |= 1ull << d; S2 += e; }
      if (cnt < 38) { mk3 |= 1ull << d; S3 += e; }
    }
    float w0 = attnw[0] / S0, w1 = attnw[1] / S1;
    float w2 = attnw[2] / S2, w3 = attnw[3] / S3;
    float* Ao = A + ((size_t)bh * 48 + c) * 48;
    for (int d = 0; d < 48; d++) {
      float e = expf(Sv[c][d] - m);
      float a = 0.f;
      if ((mk0 >> d) & 1) a += w0 * e;
      if ((mk1 >> d) & 1) a += w1 * e;
      if ((mk2 >> d) & 1) a += w2 * e;
      if ((mk3 >> d) & 1) a += w3 * e;
      Ao[d] = a;
    }
  }
}

// ---------------------------------------------------------------------------
// M[b] = w_out @ A_blockdiag[b] (192x192 per batch), emitted directly as
// packed split-bf16 hi/lo A-fragments (same k-bijection as k_wpack).
// hi at mp[(b*12+mt)*3072 + idx], lo at +147456.
// ---------------------------------------------------------------------------
__global__ __launch_bounds__(256) void k_mbuild2(
    const float* __restrict__ wout, const float* __restrict__ A,
    unsigned short* __restrict__ mp)
{
  const int mt = blockIdx.x, b = blockIdx.y;
  __shared__ float Ml[16][193];
  const int t = threadIdx.x;
  const int o = t >> 4, jg = t & 15;
#pragma unroll
  for (int e = 0; e < 12; e++) {
    int j = jg * 12 + e;
    int h = j / 48, d = j - h * 48;
    const float* wrow = wout + (mt * 16 + o) * 192 + h * 48;
    const float* Ab = A + ((size_t)(b * 4 + h) * 48) * 48 + d;
    float s = 0.f;
#pragma unroll
    for (int c2 = 0; c2 < 48; c2++) s += wrow[c2] * Ab[c2 * 48];
    Ml[o][j] = s;
  }
  __syncthreads();
  unsigned short* mpo = mp + ((size_t)b * 12 + mt) * 3072;
#pragma unroll
  for (int e = 0; e < 12; e++) {
    int idx = t * 12 + e;
    int kg = idx >> 9, rem = idx & 511, l = rem >> 3, j = rem & 7;
    int k = kg * 32 + ((l >> 4) << 2) + (j & 3) + ((j >> 2) << 4);
    float x = Ml[l & 15][k];
    unsigned short h = f2bf(x);
    mpo[idx] = h;
    mpo[147456 + idx] = f2bf(x - bf2f(h));
  }
}

// ---------------------------------------------------------------------------
extern "C" void kernel_launch(void* const* d_in, const int* in_sizes, int n_in,
                              void* d_out, int out_size, void* d_ws, size_t ws_size,
                              hipStream_t stream)
{
  const float* x     = (const float*)d_in[0];
  const float* wqkv  = (const float*)d_in[1];
  const float* wdw   = (const float*)d_in[2];
  const float* wout  = (const float*)d_in[3];
  const float* temp  = (const float*)d_in[4];
  const float* attnw = (const float*)d_in[5];
  float* outp = (float*)d_out;
  float* ws = (float*)d_ws;

  // workspace (floats) — total 38,635,008 = 147.4 MiB
  float* qkvbuf    = ws;                      // 37,748,736
  float* inorm     = ws + 37748736;           // 1,536
  float* attn_part = ws + 37750272;           // 589,824 (16 x 16 x 2304)
  float* Acomb     = ws + 38340096;           // 36,864
  unsigned short* wp16 = (unsigned short*)(ws + 38376960);  // 221,184 u16 (hi+lo)
  unsigned short* mp16 = (unsigned short*)(ws + 38487552);  // 294,912 u16 (hi+lo)

  // 1) pack w_qkv into split-bf16 A-frag layout
  k_wpack<<<216, 64, 0, stream>>>(wqkv, wp16);

  // 2) qkv = conv1x1(x, w_qkv): split-bf16 MFMA GEMM 576 x 16384 x 192
  k_gemm_sb<<<dim3(128, 3, NB), 512, 0, stream>>>(
      x, wp16, qkvbuf, (size_t)CIN * HW, 0, (size_t)C3 * HW, (size_t)110592);

  // 3) depthwise 3x3 in-place + fused q/k row-norm
  k_dwconv_norm<<<NB * C3, 256, 0, stream>>>(qkvbuf, wdw, inorm);

  // 4) attn Gram partials (16 split-K chunks)
  k_attn_part<<<dim3(16, 16), 256, 0, stream>>>(qkvbuf, attn_part);

  // 5) fused reduce + combined top-k softmax matrix A
  k_topk_combine<<<16, 64, 0, stream>>>(attn_part, inorm, temp, attnw, Acomb);

  // 6) M = w_out @ A_blockdiag, emitted as packed split-bf16 frags
  k_mbuild2<<<dim3(12, NB), 256, 0, stream>>>(wout, Acomb, mp16);

  // 7) out = M @ v: split-bf16 MFMA GEMM 192 x 16384 x 192
  k_gemm_sb<<<dim3(128, 1, NB), 512, 0, stream>>>(
      qkvbuf + (size_t)384 * HW, mp16, outp,
      (size_t)C3 * HW, (size_t)36864, (size_t)CIN * HW, (size_t)147456);
}

// Round 8
// 368.310 us; speedup vs baseline: 1.3362x; 1.2432x over previous
//
#include <hip/hip_runtime.h>
#include <hip/hip_bf16.h>

#define HW   16384
#define WIDTH 128
#define CIN  192
#define C3   576
#define NB   4
#define CH   48

typedef __attribute__((ext_vector_type(8))) __bf16 bf16x8;
typedef __attribute__((ext_vector_type(4))) float f32x4;

__device__ __forceinline__ unsigned short f2bf(float f) {
  unsigned u = __float_as_uint(f);
  unsigned r = (u + 0x7fffu + ((u >> 16) & 1u)) >> 16;   // RNE
  return (unsigned short)r;
}
__device__ __forceinline__ float bf2f(unsigned short h) {
  return __uint_as_float((unsigned)h << 16);
}

// ---------------------------------------------------------------------------
// Pack w_qkv (576x192 fp32) into MFMA A-fragment layout, split-bf16 hi/lo.
// Frag elem j of lane l, k-tile kg:  k = kg*32 + (l>>4)*4 + (j&3) + 16*(j>>2)
// (B-fragments are gathered with the same (g,j)->k bijection — consistent
// A/B k-permutation cancels inside the MFMA dot product).
// hi plane at wp[0..110591], lo plane at wp[110592..].
// ---------------------------------------------------------------------------
__global__ void k_wpack(const float* __restrict__ w, unsigned short* __restrict__ wp)
{
  const int bid = blockIdx.x;            // mt*6 + kg, mt in [0,36)
  const int mt = bid / 6, kg = bid - 6 * mt;
  const int l = threadIdx.x;             // 0..63
  const int m = mt * 16 + (l & 15);
  const int g = l >> 4;
  unsigned short vh[8], vl[8];
#pragma unroll
  for (int j = 0; j < 8; j++) {
    int k = kg * 32 + (g << 2) + (j & 3) + ((j >> 2) << 4);
    float x = w[m * 192 + k];
    vh[j] = f2bf(x);
    vl[j] = f2bf(x - bf2f(vh[j]));
  }
  *(uint4*)(wp + ((size_t)bid * 64 + l) * 8) = *(uint4*)vh;
  *(uint4*)(wp + 110592 + ((size_t)bid * 64 + l) * 8) = *(uint4*)vl;
}

// ---------------------------------------------------------------------------
// Split-bf16 MFMA channel-mix GEMM: out[b,o,p] = sum_c W[o,c] * B[b,c,p]
// x*y ~= hi*hi' + hi*lo' + lo*hi' (fp32 accum; lo*lo' <= 2^-18 dropped).
// BM=192 (3 m-frags/wave), BN=128. 512 thr = 8 waves (4 wm x 2 wn), wave
// tile 48x64. K staged in 2 halves of 96 rows. B: fp32 global -> {hi,lo}
// bf16 LDS, TRANSPOSED + padded layout Bt[pl][ns][col][k(96)+4pad] so each
// fragment is two contiguous 8-byte runs -> plain C++ uint2 reads
// (ds_read_b64), no inline asm, no address-space casts.
// A: prepacked hi/lo frags from global (L2-resident), lo at +aLoOff elems.
// ---------------------------------------------------------------------------
__global__ __launch_bounds__(512) void k_gemm_sb(
    const float* __restrict__ Bsrc, const unsigned short* __restrict__ Afrag,
    float* __restrict__ out, size_t bBatch, size_t aBatch, size_t outBatch,
    size_t aLoOff)
{
  __shared__ unsigned short Bt[2][8][16][100];   // 51.2 KB: [hi/lo][ns][col][klocal]
  const int b = blockIdx.z, mb = blockIdx.y;
  const int pBase = blockIdx.x * 128;
  const int t = threadIdx.x;
  const int lane = t & 63, w = t >> 6;
  const int wm = w >> 1, wn = w & 1;
  const int g = lane >> 4, c = lane & 15;
  const float* Bp = Bsrc + (size_t)b * bBatch + pBase;
  const unsigned short* Ap = Afrag + (size_t)b * aBatch;
  const int mtBase = mb * 12 + wm * 3;

  f32x4 acc[3][4];
#pragma unroll
  for (int i = 0; i < 3; i++)
#pragma unroll
    for (int nf = 0; nf < 4; nf++) acc[i][nf] = f32x4{0.f, 0.f, 0.f, 0.f};

  for (int kh = 0; kh < 2; kh++) {
    if (kh) __syncthreads();             // previous half's readers done
    // ---- stage: wave w owns ns=w (cols w*16..+15); 96 k-rows this half ----
    {
      const int kr = lane >> 2, nc = (lane & 3) * 4;
      const float* src = Bp + w * 16 + nc;
#pragma unroll
      for (int i = 0; i < 6; i++) {
        int kl = i * 16 + kr;            // 0..95
        float4 v = *(const float4*)&src[(size_t)(kh * 96 + kl) * HW];
        float xs[4] = {v.x, v.y, v.z, v.w};
#pragma unroll
        for (int q = 0; q < 4; q++) {
          unsigned short hh = f2bf(xs[q]);
          Bt[0][w][nc + q][kl] = hh;
          Bt[1][w][nc + q][kl] = f2bf(xs[q] - bf2f(hh));
        }
      }
    }
    __syncthreads();
    // ---- compute: 3 k-tiles of 32 within this half ----
#pragma unroll
    for (int ks = 0; ks < 3; ks++) {
      const int kg = kh * 3 + ks;        // global 32-row tile index 0..5
      bf16x8 afh[3], afl[3];
#pragma unroll
      for (int i = 0; i < 3; i++) {
        size_t fo = (((size_t)(mtBase + i) * 6 + kg) * 64 + lane) * 8;
        afh[i] = __builtin_bit_cast(bf16x8, *(const uint4*)(Ap + fo));
        afl[i] = __builtin_bit_cast(bf16x8, *(const uint4*)(Ap + aLoOff + fo));
      }
      const int k0 = ks * 32 + g * 4;    // frag k-base within half (<= 76)
#pragma unroll
      for (int nf = 0; nf < 4; nf++) {
        const int ns = wn * 4 + nf;
        const unsigned short* ch = &Bt[0][ns][c][0];
        const unsigned short* cl = &Bt[1][ns][c][0];
        uint2 h0 = *(const uint2*)(ch + k0);
        uint2 h1 = *(const uint2*)(ch + k0 + 16);
        uint2 l0 = *(const uint2*)(cl + k0);
        uint2 l1 = *(const uint2*)(cl + k0 + 16);
        uint4 bw;
        bw.x = h0.x; bw.y = h0.y; bw.z = h1.x; bw.w = h1.y;
        bf16x8 bfh = __builtin_bit_cast(bf16x8, bw);
        bw.x = l0.x; bw.y = l0.y; bw.z = l1.x; bw.w = l1.y;
        bf16x8 bfl = __builtin_bit_cast(bf16x8, bw);
#pragma unroll
        for (int i = 0; i < 3; i++) {
          acc[i][nf] = __builtin_amdgcn_mfma_f32_16x16x32_bf16(afh[i], bfl, acc[i][nf], 0, 0, 0);
          acc[i][nf] = __builtin_amdgcn_mfma_f32_16x16x32_bf16(afl[i], bfh, acc[i][nf], 0, 0, 0);
          acc[i][nf] = __builtin_amdgcn_mfma_f32_16x16x32_bf16(afh[i], bfh, acc[i][nf], 0, 0, 0);
        }
      }
    }
  }

  // ---- epilogue: C/D layout col=lane&15, row=(lane>>4)*4+reg (m89) ----
  const int r0 = g * 4, c0 = c;
  float* op = out + (size_t)b * outBatch + pBase + wn * 64 + c0;
#pragma unroll
  for (int i = 0; i < 3; i++) {
    int mrow = (mtBase + i) * 16 + r0;
#pragma unroll
    for (int nf = 0; nf < 4; nf++)
#pragma unroll
      for (int r = 0; r < 4; r++)
        op[(size_t)(mrow + r) * HW + nf * 16] = acc[i][nf][r];
  }
}

// ---------------------------------------------------------------------------
// Depthwise 3x3 conv (pad 1), IN-PLACE per plane via LDS row ring, fused with
// the q/k L2-row-norm reduction (channels 0..383 of each batch).
// ---------------------------------------------------------------------------
__global__ __launch_bounds__(256) void k_dwconv_norm(
    float* __restrict__ buf, const float* __restrict__ wdw, float* __restrict__ inorm)
{
  const int bo = blockIdx.x;          // b*576 + ch
  const int ch = bo % C3;
  const int b  = bo / C3;
  float* plane = buf + (size_t)bo * HW;
  float wv[9];
#pragma unroll
  for (int i = 0; i < 9; i++) wv[i] = wdw[ch * 9 + i];

  __shared__ float ring[16][128];
  __shared__ float red[4];
  const int tx = threadIdx.x & 31;
  const int ty = threadIdx.x >> 5;
  const int x0 = tx * 4;

  *(float4*)&ring[ty][x0] = *(const float4*)&plane[ty * WIDTH + x0];
  if (ty == 0) *(float4*)&ring[8][x0] = *(const float4*)&plane[8 * WIDTH + x0];

  float ssum = 0.f;

  for (int c = 0; c < 16; c++) {
    __syncthreads();
    const int y = c * 8 + ty;
    float a0 = 0.f, a1 = 0.f, a2 = 0.f, a3 = 0.f;
#pragma unroll
    for (int dy = 0; dy < 3; dy++) {
      int yy = y + dy - 1;
      if (yy < 0 || yy > 127) continue;
      const float* r = ring[yy & 15];
      float4 cc = *(const float4*)&r[x0];
      float left  = (x0 > 0) ? r[x0 - 1] : 0.f;
      float right = (x0 + 4 < WIDTH) ? r[x0 + 4] : 0.f;
      float w0 = wv[dy * 3 + 0], w1 = wv[dy * 3 + 1], w2 = wv[dy * 3 + 2];
      a0 += w0 * left + w1 * cc.x + w2 * cc.y;
      a1 += w0 * cc.x + w1 * cc.y + w2 * cc.z;
      a2 += w0 * cc.y + w1 * cc.z + w2 * cc.w;
      a3 += w0 * cc.z + w1 * cc.w + w2 * right;
    }
    __syncthreads();
    *(float4*)&plane[y * WIDTH + x0] = make_float4(a0, a1, a2, a3);
    ssum += a0 * a0 + a1 * a1 + a2 * a2 + a3 * a3;
    if (c < 15) {
      int rrow = c * 8 + 9 + ty;
      if (rrow < 128)
        *(float4*)&ring[rrow & 15][x0] = *(const float4*)&plane[rrow * WIDTH + x0];
    }
  }

  if (ch < 384) {
    for (int off = 32; off; off >>= 1) ssum += __shfl_down(ssum, off, 64);
    if ((threadIdx.x & 63) == 0) red[threadIdx.x >> 6] = ssum;
    __syncthreads();
    if (threadIdx.x == 0) {
      float tot = red[0] + red[1] + red[2] + red[3];
      inorm[b * 384 + ch] = 1.0f / fmaxf(sqrtf(tot), 1e-12f);
    }
  }
}

// ---------------------------------------------------------------------------
// attn partials: per (b,h) 48x48 Gram over 16384 tokens, split-K 16 chunks
// of 1024 (deterministic; no atomics). Norm/temp folded in later.
// ---------------------------------------------------------------------------
__global__ __launch_bounds__(256) void k_attn_part(
    const float* __restrict__ qkv, float* __restrict__ part)
{
  const int bh = blockIdx.y;
  const int b = bh >> 2, h = bh & 3;
  const int pbase = blockIdx.x * 1024;
  const float* qb = qkv + ((size_t)b * C3 +       h * CH) * HW + pbase;
  const float* kb = qkv + ((size_t)b * C3 + 192 + h * CH) * HW + pbase;
  __shared__ float Ql[48][33], Kl[48][33];
  const int t = threadIdx.x;
  const int c0 = (t & 15) * 3, d0 = (t >> 4) * 3;
  float acc[3][3];
#pragma unroll
  for (int i = 0; i < 3; i++)
#pragma unroll
    for (int j = 0; j < 3; j++) acc[i][j] = 0.f;

  for (int chk = 0; chk < 32; chk++) {
    const int pp0 = chk * 32;
#pragma unroll
    for (int i = 0; i < 6; i++) {
      int lin = t + i * 256;
      int cc = lin >> 5, pp = lin & 31;
      Ql[cc][pp] = qb[(size_t)cc * HW + pp0 + pp];
      Kl[cc][pp] = kb[(size_t)cc * HW + pp0 + pp];
    }
    __syncthreads();
#pragma unroll
    for (int pp = 0; pp < 32; pp++) {
      float q0 = Ql[c0][pp], q1 = Ql[c0 + 1][pp], q2 = Ql[c0 + 2][pp];
      float k0v = Kl[d0][pp], k1v = Kl[d0 + 1][pp], k2v = Kl[d0 + 2][pp];
      acc[0][0] += q0 * k0v; acc[0][1] += q0 * k1v; acc[0][2] += q0 * k2v;
      acc[1][0] += q1 * k0v; acc[1][1] += q1 * k1v; acc[1][2] += q1 * k2v;
      acc[2][0] += q2 * k0v; acc[2][1] += q2 * k1v; acc[2][2] += q2 * k2v;
    }
    __syncthreads();
  }
  float* pb = part + ((size_t)blockIdx.x * 16 + bh) * 2304;
#pragma unroll
  for (int i = 0; i < 3; i++)
#pragma unroll
    for (int j = 0; j < 3; j++)
      pb[(c0 + i) * 48 + d0 + j] = acc[i][j];
}

// ---------------------------------------------------------------------------
// Deterministic split-K reduce: attn_raw[idx] = sum over 16 partials.
// ---------------------------------------------------------------------------
__global__ __launch_bounds__(256) void k_attn_reduce(
    const float* __restrict__ part, float* __restrict__ attn)
{
  int idx = blockIdx.x * 256 + threadIdx.x;   // 36864 total
  float s = 0.f;
#pragma unroll
  for (int ps = 0; ps < 16; ps++) s += part[(size_t)ps * 36864 + idx];
  attn[idx] = s;
}

// ---------------------------------------------------------------------------
// Wave-parallel: apply inorm/temp scale, rank all 48 entries (tie-break by
// index == lax.top_k), 4-way masked softmax combine weighted by attn_w.
// One block (4 waves) per (b,h); each wave owns 12 rows; lane d owns elem d.
// ---------------------------------------------------------------------------
__global__ __launch_bounds__(256) void k_topk2(
    const float* __restrict__ attn, const float* __restrict__ inorm,
    const float* __restrict__ temp, const float* __restrict__ attnw,
    float* __restrict__ A)
{
  const int bh = blockIdx.x;
  const int b = bh >> 2, h = bh & 3;
  __shared__ float Sv[48][49];
  const float tmp = temp[h];
  const int tid = threadIdx.x;
  const float* ar = attn + (size_t)bh * 2304;
#pragma unroll
  for (int k = 0; k < 9; k++) {
    int i = tid + k * 256;
    int c = i / 48, d = i - (i / 48) * 48;
    Sv[c][d] = ar[i] * inorm[b * 384 + h * 48 + c]
                     * inorm[b * 384 + 192 + h * 48 + d] * tmp;
  }
  __syncthreads();
  const float w0 = attnw[0], w1 = attnw[1], w2 = attnw[2], w3 = attnw[3];
  const int wv = tid >> 6, d = tid & 63;
  for (int r = 0; r < 12; r++) {
    const int c = wv * 12 + r;
    float vd = (d < 48) ? Sv[c][d] : -3.4e38f;
    float m = vd;
#pragma unroll
    for (int off = 32; off; off >>= 1) m = fmaxf(m, __shfl_xor(m, off, 64));
    int cnt = 0;
    for (int d2 = 0; d2 < 48; d2++) {           // LDS broadcast reads
      float v2 = Sv[c][d2];
      cnt += (v2 > vd) || (v2 == vd && d2 < d);
    }
    float e = (d < 48) ? expf(vd - m) : 0.f;    // lanes >=48: cnt=48 -> e unused
    float S0 = (cnt < 24) ? e : 0.f;
    float S1 = (cnt < 32) ? e : 0.f;
    float S2 = (cnt < 36) ? e : 0.f;
    float S3 = (cnt < 38) ? e : 0.f;
#pragma unroll
    for (int off = 32; off; off >>= 1) {
      S0 += __shfl_xor(S0, off, 64);
      S1 += __shfl_xor(S1, off, 64);
      S2 += __shfl_xor(S2, off, 64);
      S3 += __shfl_xor(S3, off, 64);
    }
    if (d < 48) {
      float a = 0.f;
      if (cnt < 24) a += w0 / S0 * e;
      if (cnt < 32) a += w1 / S1 * e;
      if (cnt < 36) a += w2 / S2 * e;
      if (cnt < 38) a += w3 / S3 * e;
      A[((size_t)bh * 48 + c) * 48 + d] = a;
    }
  }
}

// ---------------------------------------------------------------------------
// M[b] = w_out @ A_blockdiag[b] (192x192 per batch), emitted directly as
// packed split-bf16 hi/lo A-fragments (same k-bijection as k_wpack).
// hi at mp[(b*12+mt)*3072 + idx], lo at +147456.
// ---------------------------------------------------------------------------
__global__ __launch_bounds__(256) void k_mbuild2(
    const float* __restrict__ wout, const float* __restrict__ A,
    unsigned short* __restrict__ mp)
{
  const int mt = blockIdx.x, b = blockIdx.y;
  __shared__ float Ml[16][193];
  const int t = threadIdx.x;
  const int o = t >> 4, jg = t & 15;
#pragma unroll
  for (int e = 0; e < 12; e++) {
    int j = jg * 12 + e;
    int h = j / 48, d = j - h * 48;
    const float* wrow = wout + (mt * 16 + o) * 192 + h * 48;
    const float* Ab = A + ((size_t)(b * 4 + h) * 48) * 48 + d;
    float s = 0.f;
#pragma unroll
    for (int c2 = 0; c2 < 48; c2++) s += wrow[c2] * Ab[c2 * 48];
    Ml[o][j] = s;
  }
  __syncthreads();
  unsigned short* mpo = mp + ((size_t)b * 12 + mt) * 3072;
#pragma unroll
  for (int e = 0; e < 12; e++) {
    int idx = t * 12 + e;
    int kg = idx >> 9, rem = idx & 511, l = rem >> 3, j = rem & 7;
    int k = kg * 32 + ((l >> 4) << 2) + (j & 3) + ((j >> 2) << 4);
    float x = Ml[l & 15][k];
    unsigned short h = f2bf(x);
    mpo[idx] = h;
    mpo[147456 + idx] = f2bf(x - bf2f(h));
  }
}

// ---------------------------------------------------------------------------
extern "C" void kernel_launch(void* const* d_in, const int* in_sizes, int n_in,
                              void* d_out, int out_size, void* d_ws, size_t ws_size,
                              hipStream_t stream)
{
  const float* x     = (const float*)d_in[0];
  const float* wqkv  = (const float*)d_in[1];
  const float* wdw   = (const float*)d_in[2];
  const float* wout  = (const float*)d_in[3];
  const float* temp  = (const float*)d_in[4];
  const float* attnw = (const float*)d_in[5];
  float* outp = (float*)d_out;
  float* ws = (float*)d_ws;

  // workspace (floats) — total 38,671,872 = 147.5 MiB
  float* qkvbuf    = ws;                      // 37,748,736
  float* inorm     = ws + 37748736;           // 1,536
  float* attn_part = ws + 37750272;           // 589,824 (16 x 16 x 2304)
  float* Acomb     = ws + 38340096;           // 36,864
  unsigned short* wp16 = (unsigned short*)(ws + 38376960);  // 221,184 u16 (hi+lo)
  unsigned short* mp16 = (unsigned short*)(ws + 38487552);  // 294,912 u16 (hi+lo)
  float* attn_raw  = ws + 38635008;           // 36,864

  // 1) pack w_qkv into split-bf16 A-frag layout
  k_wpack<<<216, 64, 0, stream>>>(wqkv, wp16);

  // 2) qkv = conv1x1(x, w_qkv): split-bf16 MFMA GEMM 576 x 16384 x 192
  k_gemm_sb<<<dim3(128, 3, NB), 512, 0, stream>>>(
      x, wp16, qkvbuf, (size_t)CIN * HW, 0, (size_t)C3 * HW, (size_t)110592);

  // 3) depthwise 3x3 in-place + fused q/k row-norm
  k_dwconv_norm<<<NB * C3, 256, 0, stream>>>(qkvbuf, wdw, inorm);

  // 4) attn Gram partials (16 split-K chunks)
  k_attn_part<<<dim3(16, 16), 256, 0, stream>>>(qkvbuf, attn_part);

  // 5) deterministic split-K reduce (parallel)
  k_attn_reduce<<<144, 256, 0, stream>>>(attn_part, attn_raw);

  // 6) wave-parallel combined top-k softmax matrix A
  k_topk2<<<16, 256, 0, stream>>>(attn_raw, inorm, temp, attnw, Acomb);

  // 7) M = w_out @ A_blockdiag, emitted as packed split-bf16 frags
  k_mbuild2<<<dim3(12, NB), 256, 0, stream>>>(wout, Acomb, mp16);

  // 8) out = M @ v: split-bf16 MFMA GEMM 192 x 16384 x 192
  k_gemm_sb<<<dim3(128, 1, NB), 512, 0, stream>>>(
      qkvbuf + (size_t)384 * HW, mp16, outp,
      (size_t)C3 * HW, (size_t)36864, (size_t)CIN * HW, (size_t)147456);
}